// Round 2
// baseline (218.826 us; speedup 1.0000x reference)
//
#include <hip/hip_runtime.h>
#include <hip/hip_fp16.h>
#include <math.h>

#define N_NODES 50000
#define N_REL   1000
#define D       128
#define NNZ     800000

#define NTHR 512
#define NB1  1024                  // 4 blocks/CU on 256 CUs -> 32 waves/CU
#define TS   2048                  // scan tile size (4 elems/thread)
#define NT   25                    // ceil(50000/2048)
#define CNTP (NT * TS)             // 51200 padded count array

// ======== K1: fused relation scores + f32->f16 convert + row-count histogram ========
__global__ void __launch_bounds__(NTHR)
k1_kernel(const int* __restrict__ rows, const float* __restrict__ dual,
          const float* __restrict__ conv_w, const float* __restrict__ conv_b,
          const float* __restrict__ inlayer, float* __restrict__ exp_scores,
          unsigned* __restrict__ cnt, __half2* __restrict__ hinl) {
    int t = threadIdx.x;
    int gtid = blockIdx.x * NTHR + t;
    int lane = t & 63;

    // scores: one wave per relation (first 1000 waves)
    int wid = gtid >> 6;
    if (wid < N_REL) {
        const float* row = dual + (long)wid * D;
        float s = row[lane] * conv_w[lane] + row[lane + 64] * conv_w[lane + 64];
        #pragma unroll
        for (int off = 32; off > 0; off >>= 1) s += __shfl_down(s, off);
        if (lane == 0) {
            float v = s + conv_b[0];
            v = (v >= 0.f) ? v : 0.01f * v;            // leaky_relu
            exp_scores[wid] = expf(v);                 // scores ~N(0,1): safe
        }
    }

    // f32 -> f16 convert (grid-stride, float4 -> 2x half2, coalesced)
    const float4* src4 = (const float4*)inlayer;
    uint2* dst2 = (uint2*)hinl;
    for (int i = gtid; i < N_NODES * D / 4; i += NB1 * NTHR) {
        float4 f = src4[i];
        __half2 h0 = __floats2half2_rn(f.x, f.y);
        __half2 h1 = __floats2half2_rn(f.z, f.w);
        uint2 o; o.x = *(unsigned*)&h0; o.y = *(unsigned*)&h1;
        dst2[i] = o;
    }

    // row-count histogram: 1 edge/thread, ~1.5 grid-stride iters at 32 waves/CU
    for (int i = gtid; i < NNZ; i += NB1 * NTHR)
        atomicAdd(&cnt[rows[i]], 1u);
}

// ======== K2: in-place exclusive scan of cnt[50000] (decoupled lookback, 25 tiles) ====
__global__ void __launch_bounds__(NTHR)
scan_kernel(unsigned* __restrict__ cnt, unsigned long long* __restrict__ state,
            unsigned* __restrict__ ticket) {
    __shared__ unsigned wsum[8];
    __shared__ unsigned sh_agg, sh_base;
    __shared__ int sh_tile;
    int t = threadIdx.x, lane = t & 63, w = t >> 6;

    if (t == 0) sh_tile = (int)atomicAdd(ticket, 1u);
    __syncthreads();
    int tile = sh_tile;

    int base = tile * TS + t * 4;          // always < CNTP (padded, zeroed)
    uint4 x = *(uint4*)&cnt[base];
    unsigned run = x.x + x.y + x.z + x.w;

    unsigned v = run;                      // wave-inclusive scan of thread sums
    #pragma unroll
    for (int off = 1; off < 64; off <<= 1) {
        unsigned y = __shfl_up(v, off);
        if (lane >= off) v += y;
    }
    if (lane == 63) wsum[w] = v;
    __syncthreads();
    if (t == 0) {
        unsigned acc = 0;
        #pragma unroll
        for (int k = 0; k < 8; ++k) { unsigned tmp = wsum[k]; wsum[k] = acc; acc += tmp; }
        sh_agg = acc;
    }
    __syncthreads();
    unsigned tbase = wsum[w] + (v - run);  // exclusive base for this thread

    if (t == 0)
        atomicExch(&state[tile], (1ULL << 32) | (unsigned long long)sh_agg);
    if (t < 64) {
        unsigned sum = 0;
        if (tile > 0) {
            int base_pred = tile - 1;
            for (;;) {
                int pred = base_pred - t;
                unsigned long long sv;
                if (pred >= 0) {
                    do { sv = atomicAdd(&state[pred], 0ULL); } while ((sv >> 32) == 0ULL);
                } else {
                    sv = (2ULL << 32);
                }
                unsigned long long m2 = __ballot((sv >> 32) == 2ULL);
                int l2 = (m2 != 0ULL) ? (__ffsll((long long)m2) - 1) : 64;
                unsigned contrib = ((int)t <= l2) ? (unsigned)sv : 0u;
                #pragma unroll
                for (int off = 32; off > 0; off >>= 1)
                    contrib += __shfl_down(contrib, off);
                sum += __shfl(contrib, 0);
                if (m2 != 0ULL) break;
                base_pred -= 64;
            }
        }
        if (t == 0) {
            sh_base = sum;
            atomicExch(&state[tile],
                       (2ULL << 32) | (unsigned long long)(sum + sh_agg));
        }
    }
    __syncthreads();
    unsigned g = sh_base + tbase;
    uint4 o;
    o.x = g; o.y = g + x.x; o.z = g + x.x + x.y; o.w = g + x.x + x.y + x.z;
    *(uint4*)&cnt[base] = o;
}

// ======== K3: place edges via atomic cursors on starts[]; fused denom reduction ======
__global__ void __launch_bounds__(NTHR)
place_kernel(const int* __restrict__ rows, const int* __restrict__ cols,
             const int* __restrict__ rel, const float* __restrict__ exp_scores,
             unsigned* __restrict__ starts, int2* __restrict__ bpack,
             float* __restrict__ denom) {
    __shared__ float fpart[8];
    int t = threadIdx.x;
    int gtid = blockIdx.x * NTHR + t;
    int lane = t & 63, w = t >> 6;
    float dsum = 0.f;
    // 1 edge/thread grid-stride: short dependency chain, latency spread across waves
    for (int i = gtid; i < NNZ; i += NB1 * NTHR) {
        int r = rows[i];
        int c = cols[i];
        int q = rel[i];
        float wv = exp_scores[q];                  // 4KB table: cache-resident
        dsum += wv;
        unsigned pos = atomicAdd(&starts[r], 1u);  // exclusive -> inclusive
        int2 pk; pk.x = c; pk.y = __float_as_int(wv);  // unnormalized weight
        bpack[pos] = pk;
    }
    #pragma unroll
    for (int off = 32; off > 0; off >>= 1) dsum += __shfl_down(dsum, off);
    if (lane == 0) fpart[w] = dsum;
    __syncthreads();
    if (t == 0) {
        float s = 0.f;
        #pragma unroll
        for (int k = 0; k < 8; ++k) s += fpart[k];
        atomicAdd(denom, s);
    }
}

// ======== K4: gather — fp16 rows, 16 lanes/row, 4 rows per load; /denom epilogue =====
__global__ void gather_kernel(const unsigned* __restrict__ starts,
                              const int2* __restrict__ bpack,
                              const __half2* __restrict__ hinl,
                              const float* __restrict__ denom,
                              float* __restrict__ out) {
    int node = blockIdx.x * (blockDim.x >> 6) + (threadIdx.x >> 6);
    int lane = threadIdx.x & 63;
    if (node >= N_NODES) return;
    // after place_kernel, starts[] is the INCLUSIVE prefix: seg = [starts[n-1], starts[n])
    int e = (int)starts[node];
    int s = (node > 0) ? (int)starts[node - 1] : 0;
    int quad = lane >> 4;                  // which of 4 rows per load
    int l16  = lane & 15;                  // 8-dim group within row
    float a0=0.f,a1=0.f,a2=0.f,a3=0.f,a4=0.f,a5=0.f,a6=0.f,a7=0.f;
    for (int base = s; base < e; base += 64) {
        int rem = e - base; if (rem > 64) rem = 64;
        int px = 0, py = 0;
        if (lane < rem) {
            int2 p = bpack[base + lane];   // coalesced 512B / 64 edges
            px = p.x; py = p.y;
        }
        for (int j = 0; j < rem; j += 16) {
            #pragma unroll
            for (int k = 0; k < 16; k += 4) {
                if (j + k < rem) {         // wave-uniform guard
                    int idx = j + k + quad;
                    int   c = __shfl(px, idx);           // 0 beyond rem -> w=0
                    float w = __int_as_float(__shfl(py, idx));
                    const __half2* hp = hinl + (long)c * (D / 2) + l16 * 4;
                    uint4 hv = *(const uint4*)hp;        // 8 halves (16B)
                    float2 f0 = __half22float2(*(const __half2*)&hv.x);
                    float2 f1 = __half22float2(*(const __half2*)&hv.y);
                    float2 f2 = __half22float2(*(const __half2*)&hv.z);
                    float2 f3 = __half22float2(*(const __half2*)&hv.w);
                    a0 += w * f0.x; a1 += w * f0.y;
                    a2 += w * f1.x; a3 += w * f1.y;
                    a4 += w * f2.x; a5 += w * f2.y;
                    a6 += w * f3.x; a7 += w * f3.y;
                }
            }
        }
    }
    // combine the 4 quads: butterfly over lane bits 4 and 5
    #define COMB(x) x += __shfl(x, lane ^ 16); x += __shfl(x, lane ^ 32);
    COMB(a0) COMB(a1) COMB(a2) COMB(a3) COMB(a4) COMB(a5) COMB(a6) COMB(a7)
    #undef COMB
    if (lane < 32) {                       // 32 lanes cover the 512B row store
        float inv = 1.0f / *denom;         // normalization deferred to epilogue
        float4 v;
        int hi = (lane >> 4) & 1;          // 0: dims 0-3 of group, 1: dims 4-7
        if (hi) { v.x = a4*inv; v.y = a5*inv; v.z = a6*inv; v.w = a7*inv; }
        else    { v.x = a0*inv; v.y = a1*inv; v.z = a2*inv; v.w = a3*inv; }
        *(float4*)(out + (long)node * D + l16 * 8 + hi * 4) = v;
    }
}

extern "C" void kernel_launch(void* const* d_in, const int* in_sizes, int n_in,
                              void* d_out, int out_size, void* d_ws, size_t ws_size,
                              hipStream_t stream) {
    const float* inlayer  = (const float*)d_in[0];
    const float* dual     = (const float*)d_in[1];
    const float* conv_w   = (const float*)d_in[2];
    const float* conv_b   = (const float*)d_in[3];
    const int*   edge_idx = (const int*)d_in[4];   // [2, NNZ]: rows then cols
    const int*   edge_rel = (const int*)d_in[5];
    float* out = (float*)d_out;
    const int* rows = edge_idx;
    const int* cols = edge_idx + NNZ;

    // workspace layout (16B aligned) — total ~19.5 MB
    char* ws = (char*)d_ws;
    float*              exp_scores = (float*)             (ws);             // 4 KB
    float*              denom      = (float*)             (ws + 4096);
    unsigned*           ticket     = (unsigned*)          (ws + 4160);
    unsigned long long* state      = (unsigned long long*)(ws + 4224);      // 25*8 B
    unsigned*           cnt        = (unsigned*)          (ws + 8192);      // 204.8 KB (padded to 51200)
    int2*               bpack      = (int2*)              (ws + 8192 + CNTP * 4);           // 6.4 MB
    __half2*            hinl       = (__half2*)           (ws + 8192 + CNTP * 4 + 8 * NNZ); // 12.8 MB

    // zero denom + ticket + state + cnt (incl. padding) in one 209 KB fill
    hipMemsetAsync(ws + 4096, 0, 4096 + CNTP * 4, stream);

    k1_kernel<<<NB1, NTHR, 0, stream>>>(rows, dual, conv_w, conv_b, inlayer,
                                        exp_scores, cnt, hinl);
    scan_kernel<<<NT, NTHR, 0, stream>>>(cnt, state, ticket);
    place_kernel<<<NB1, NTHR, 0, stream>>>(rows, cols, edge_rel, exp_scores,
                                           cnt, bpack, denom);
    int grid = (N_NODES + 3) / 4;   // 4 waves/block, one node per wave
    gather_kernel<<<grid, 256, 0, stream>>>(cnt, bpack, hinl, denom, out);
}

// Round 3
// 154.409 us; speedup vs baseline: 1.4172x; 1.4172x over previous
//
#include <hip/hip_runtime.h>
#include <hip/hip_fp16.h>
#include <math.h>

#define N_NODES 50000
#define N_REL   1000
#define D       128
#define NNZ     800000

#define RB    512                  // rows per bin
#define NBIN  98                   // ceil(50000/512)
#define CAP   10240                // slots/bin: mean 8192, sigma ~90 -> 22-sigma margin
#define CH    1024                 // edges per partition chunk
#define NCH   ((NNZ + CH - 1) / CH)   // 782 chunks/blocks
#define K1T   256
#define K1E   (CH / K1T)           // 4 edges/thread
#define PBT   512

// ===== K1: scores + f32->f16 convert + LDS-sorted bin partition (coalesced runs) =====
__global__ void __launch_bounds__(K1T)
k1_kernel(const int* __restrict__ rows, const int* __restrict__ cols,
          const int* __restrict__ rel, const float* __restrict__ dual,
          const float* __restrict__ conv_w, const float* __restrict__ conv_b,
          const float* __restrict__ inlayer, float* __restrict__ exp_scores,
          unsigned* __restrict__ bincur, unsigned long long* __restrict__ binbuf,
          __half2* __restrict__ hinl) {
    __shared__ unsigned long long sbuf[CH];     // 8 KB chunk staging (bin-sorted)
    __shared__ unsigned char sbin[CH];          // 1 KB per-slot bin id
    __shared__ unsigned lcnt[NBIN], lstart[NBIN], lgb[NBIN];
    __shared__ unsigned w0sum;
    int t = threadIdx.x;
    int gtid = blockIdx.x * K1T + t;
    int lane = t & 63;

    // --- relation scores: one wave per relation (first 1000 waves of the grid) ---
    int wid = gtid >> 6;
    if (wid < N_REL) {
        const float* row = dual + (long)wid * D;
        float s = row[lane] * conv_w[lane] + row[lane + 64] * conv_w[lane + 64];
        #pragma unroll
        for (int off = 32; off > 0; off >>= 1) s += __shfl_down(s, off);
        if (lane == 0) {
            float v = s + conv_b[0];
            v = (v >= 0.f) ? v : 0.01f * v;        // leaky_relu
            exp_scores[wid] = expf(v);             // scores ~N(0,1): safe
        }
    }

    // --- f32 -> f16 convert (grid-stride float4, coalesced) ---
    const float4* src4 = (const float4*)inlayer;
    uint2* dst2 = (uint2*)hinl;
    for (int i = gtid; i < N_NODES * D / 4; i += NCH * K1T) {
        float4 f = src4[i];
        __half2 h0 = __floats2half2_rn(f.x, f.y);
        __half2 h1 = __floats2half2_rn(f.z, f.w);
        uint2 o; o.x = *(unsigned*)&h0; o.y = *(unsigned*)&h1;
        dst2[i] = o;
    }

    // --- partition this block's 1024-edge chunk ---
    for (int i = t; i < NBIN; i += K1T) lcnt[i] = 0;
    __syncthreads();

    int base = blockIdx.x * CH;
    int n = NNZ - base; if (n > CH) n = CH;      // tail chunk = 256

    int       ebin[K1E];
    unsigned  erank[K1E];
    unsigned long long epack[K1E];
    #pragma unroll
    for (int k = 0; k < K1E; ++k) {
        int j = k * K1T + t;
        if (j < n) {
            int e = base + j;
            int r = rows[e], c = cols[e], q = rel[e];
            int b = r >> 9;
            epack[k] = (unsigned long long)(unsigned)c
                     | ((unsigned long long)(unsigned)q << 16)
                     | ((unsigned long long)(unsigned)(r & 511) << 26);
            ebin[k] = b;
            erank[k] = atomicAdd(&lcnt[b], 1u);
        } else ebin[k] = -1;
    }
    __syncthreads();

    // scan 98 bin counts (2 waves) + reserve global runs
    unsigned v = (t < NBIN) ? lcnt[t] : 0u;
    if (t < 128) {
        #pragma unroll
        for (int off = 1; off < 64; off <<= 1) {
            unsigned y = __shfl_up(v, off);
            if (lane >= off) v += y;
        }
        if (t == 63) w0sum = v;
    }
    __syncthreads();
    if (t >= 64 && t < 128) v += w0sum;
    if (t < NBIN) {
        lstart[t] = v - lcnt[t];
        lgb[t] = atomicAdd(&bincur[t * 16], lcnt[t]);   // padded cursors: 1/line
    }
    __syncthreads();

    // LDS scatter into bin-sorted order
    #pragma unroll
    for (int k = 0; k < K1E; ++k) {
        if (ebin[k] >= 0) {
            unsigned p = lstart[ebin[k]] + erank[k];
            sbuf[p] = epack[k];
            sbin[p] = (unsigned char)ebin[k];
        }
    }
    __syncthreads();

    // coalesced run writes: consecutive sorted slots -> consecutive global addrs
    #pragma unroll
    for (int k = 0; k < K1E; ++k) {
        int j = k * K1T + t;
        if (j < n) {
            int b = sbin[j];
            unsigned slot = lgb[b] + (unsigned)j - lstart[b];
            if (slot < CAP)
                binbuf[(unsigned long long)b * CAP + slot] = sbuf[j];
        }
    }
}

// ===== K2: per-bin place — LDS histogram/scan/cursors; writes starts + 4B packs =====
__global__ void __launch_bounds__(PBT)
place_kernel(const unsigned* __restrict__ bincur,
             const unsigned long long* __restrict__ binbuf,
             const float* __restrict__ exp_scores,
             unsigned* __restrict__ starts, unsigned* __restrict__ bpack,
             float* __restrict__ denom) {
    __shared__ unsigned cnt[RB], cur[RB], ex[RB];
    __shared__ unsigned wsum[8];
    __shared__ float    rpart[8];
    __shared__ unsigned sh_binbase;
    int t = threadIdx.x, lane = t & 63, w = t >> 6;
    int b = blockIdx.x;
    int rlo = b * RB;
    unsigned nb = bincur[b * 16]; if (nb > CAP) nb = CAP;
    const unsigned long long* bb = binbuf + (unsigned long long)b * CAP;

    cnt[t] = 0; cur[t] = 0;
    __syncthreads();
    for (int e = t; e < (int)nb; e += PBT) {
        unsigned long long pk = bb[e];
        atomicAdd(&cnt[(pk >> 26) & 511ULL], 1u);
    }
    __syncthreads();

    // bin base = sum of earlier bins' counts (512-thread reduce)
    {
        unsigned bv = (t < b) ? min(bincur[t * 16], (unsigned)CAP) : 0u;
        #pragma unroll
        for (int off = 32; off > 0; off >>= 1) bv += __shfl_down(bv, off);
        if (lane == 0) wsum[w] = bv;
        __syncthreads();
        if (t == 0) {
            unsigned s = 0;
            #pragma unroll
            for (int k = 0; k < 8; ++k) s += wsum[k];
            sh_binbase = s;
        }
        __syncthreads();
    }

    // exclusive scan of 512 row counts (8 waves + combine)
    unsigned c0 = cnt[t];
    unsigned v = c0;
    #pragma unroll
    for (int off = 1; off < 64; off <<= 1) {
        unsigned y = __shfl_up(v, off);
        if (lane >= off) v += y;
    }
    if (lane == 63) wsum[w] = v;
    __syncthreads();
    if (t == 0) {
        unsigned acc = 0;
        #pragma unroll
        for (int k = 0; k < 8; ++k) { unsigned tmp = wsum[k]; wsum[k] = acc; acc += tmp; }
    }
    __syncthreads();
    unsigned gex = sh_binbase + wsum[w] + (v - c0);
    ex[t] = gex;
    if (rlo + t <= N_NODES) starts[rlo + t] = gex;   // includes sentinel at 50000
    __syncthreads();

    // place edges: LDS cursors; scattered 4B writes within ~32KB L2-hot window
    float dsum = 0.f;
    for (int e = t; e < (int)nb; e += PBT) {
        unsigned long long pk = bb[e];                 // L2-hot re-read
        int r = (int)((pk >> 26) & 511ULL);
        unsigned lp = (unsigned)(pk & 0x3FFFFFFULL);   // col | rel<<16
        unsigned rank = atomicAdd(&cur[r], 1u);
        bpack[ex[r] + rank] = lp;
        dsum += exp_scores[lp >> 16];
    }
    #pragma unroll
    for (int off = 32; off > 0; off >>= 1) dsum += __shfl_down(dsum, off);
    if (lane == 0) rpart[w] = dsum;
    __syncthreads();
    if (t == 0) {
        float s = 0.f;
        #pragma unroll
        for (int k = 0; k < 8; ++k) s += rpart[k];
        atomicAdd(denom, s);
    }
}

// ===== K3: gather — fp16 rows, 16 lanes/row, 4 rows per load; /denom epilogue =====
__global__ void gather_kernel(const unsigned* __restrict__ starts,
                              const unsigned* __restrict__ bpack,
                              const float* __restrict__ exp_scores,
                              const __half2* __restrict__ hinl,
                              const float* __restrict__ denom,
                              float* __restrict__ out) {
    int node = blockIdx.x * (blockDim.x >> 6) + (threadIdx.x >> 6);
    int lane = threadIdx.x & 63;
    if (node >= N_NODES) return;
    int s = (int)starts[node];
    int e = (int)starts[node + 1];
    int quad = lane >> 4;                  // which of 4 rows per load
    int l16  = lane & 15;                  // 8-dim group within row
    float a0=0.f,a1=0.f,a2=0.f,a3=0.f,a4=0.f,a5=0.f,a6=0.f,a7=0.f;
    for (int base = s; base < e; base += 64) {
        int rem = e - base; if (rem > 64) rem = 64;
        int px = 0, py = 0;
        if (lane < rem) {
            unsigned pk = bpack[base + lane];          // coalesced 256B / 64 edges
            px = (int)(pk & 0xFFFFu);
            py = __float_as_int(exp_scores[pk >> 16]); // 4KB table: L1-resident
        }
        for (int j = 0; j < rem; j += 16) {
            #pragma unroll
            for (int k = 0; k < 16; k += 4) {
                if (j + k < rem) {         // wave-uniform guard
                    int idx = j + k + quad;
                    int   c = __shfl(px, idx);           // 0 beyond rem -> w=0
                    float wv = __int_as_float(__shfl(py, idx));
                    const __half2* hp = hinl + (long)c * (D / 2) + l16 * 4;
                    uint4 hv = *(const uint4*)hp;        // 8 halves (16B)
                    float2 f0 = __half22float2(*(const __half2*)&hv.x);
                    float2 f1 = __half22float2(*(const __half2*)&hv.y);
                    float2 f2 = __half22float2(*(const __half2*)&hv.z);
                    float2 f3 = __half22float2(*(const __half2*)&hv.w);
                    a0 += wv * f0.x; a1 += wv * f0.y;
                    a2 += wv * f1.x; a3 += wv * f1.y;
                    a4 += wv * f2.x; a5 += wv * f2.y;
                    a6 += wv * f3.x; a7 += wv * f3.y;
                }
            }
        }
    }
    #define COMB(x) x += __shfl(x, lane ^ 16); x += __shfl(x, lane ^ 32);
    COMB(a0) COMB(a1) COMB(a2) COMB(a3) COMB(a4) COMB(a5) COMB(a6) COMB(a7)
    #undef COMB
    if (lane < 32) {                       // 32 lanes cover the 512B row store
        float inv = 1.0f / *denom;         // normalization deferred to epilogue
        float4 v;
        int hi = (lane >> 4) & 1;
        if (hi) { v.x = a4*inv; v.y = a5*inv; v.z = a6*inv; v.w = a7*inv; }
        else    { v.x = a0*inv; v.y = a1*inv; v.z = a2*inv; v.w = a3*inv; }
        *(float4*)(out + (long)node * D + l16 * 8 + hi * 4) = v;
    }
}

extern "C" void kernel_launch(void* const* d_in, const int* in_sizes, int n_in,
                              void* d_out, int out_size, void* d_ws, size_t ws_size,
                              hipStream_t stream) {
    const float* inlayer  = (const float*)d_in[0];
    const float* dual     = (const float*)d_in[1];
    const float* conv_w   = (const float*)d_in[2];
    const float* conv_b   = (const float*)d_in[3];
    const int*   edge_idx = (const int*)d_in[4];   // [2, NNZ]: rows then cols
    const int*   edge_rel = (const int*)d_in[5];
    float* out = (float*)d_out;
    const int* rows = edge_idx;
    const int* cols = edge_idx + NNZ;

    // workspace layout (16B aligned) — total ~24.3 MB
    char* ws = (char*)d_ws;
    float*              exp_scores = (float*)             (ws);                 // 4 KB
    float*              denom      = (float*)             (ws + 4096);          // 4 B
    unsigned*           bincur     = (unsigned*)          (ws + 8192);          // 98*16 u32 (line-padded)
    unsigned*           starts     = (unsigned*)          (ws + 16384);         // 50001 u32
    unsigned long long* binbuf     = (unsigned long long*)(ws + 221184);        // 98*10240*8 = 8.03 MB
    unsigned*           bpack      = (unsigned*)          (ws + 8249344);       // 3.2 MB
    __half2*            hinl       = (__half2*)           (ws + 11449344);      // 12.8 MB

    // zero denom + bincur in one ~10 KB fill
    hipMemsetAsync(ws + 4096, 0, 4096 + 98 * 16 * 4, stream);

    k1_kernel<<<NCH, K1T, 0, stream>>>(rows, cols, edge_rel, dual, conv_w, conv_b,
                                       inlayer, exp_scores, bincur, binbuf, hinl);
    place_kernel<<<NBIN, PBT, 0, stream>>>(bincur, binbuf, exp_scores,
                                           starts, bpack, denom);
    int grid = (N_NODES + 3) / 4;   // 4 waves/block, one node per wave
    gather_kernel<<<grid, 256, 0, stream>>>(starts, bpack, exp_scores,
                                            hinl, denom, out);
}

// Round 4
// 143.323 us; speedup vs baseline: 1.5268x; 1.0773x over previous
//
#include <hip/hip_runtime.h>
#include <hip/hip_fp16.h>
#include <math.h>

#define N_NODES 50000
#define N_REL   1000
#define D       128
#define NNZ     800000

#define RB    128                  // rows per bin
#define NBIN  391                  // ceil(50000/128)
#define CAP   2560                 // slots/bin: mean 2046, sigma ~45 -> 11-sigma margin
#define CH    2048                 // edges per partition chunk
#define NCH   ((NNZ + CH - 1) / CH)   // 391 chunks/blocks
#define K1T   512
#define K1E   (CH / K1T)           // 4 edges/thread
#define PBT   512
#define PE    (CAP / PBT)          // 5 staged edges/thread

// ===== K1: scores + f32->f16 convert + LDS-sorted bin partition (coalesced runs) =====
__global__ void __launch_bounds__(K1T)
k1_kernel(const int* __restrict__ rows, const int* __restrict__ cols,
          const int* __restrict__ rel, const float* __restrict__ dual,
          const float* __restrict__ conv_w, const float* __restrict__ conv_b,
          const float* __restrict__ inlayer, float* __restrict__ exp_scores,
          unsigned* __restrict__ bincur, unsigned long long* __restrict__ binbuf,
          __half2* __restrict__ hinl) {
    __shared__ unsigned long long sbuf[CH];     // 16 KB chunk staging (bin-sorted)
    __shared__ unsigned short sbin[CH];         // 4 KB per-slot bin id
    __shared__ unsigned lcnt[NBIN], lstart[NBIN], lgb[NBIN];
    __shared__ unsigned wsum[8];
    int t = threadIdx.x;
    int gtid = blockIdx.x * K1T + t;
    int lane = t & 63, w = t >> 6;

    // --- relation scores: one wave per relation (first 1000 waves of the grid) ---
    int wid = gtid >> 6;
    if (wid < N_REL) {
        const float* row = dual + (long)wid * D;
        float s = row[lane] * conv_w[lane] + row[lane + 64] * conv_w[lane + 64];
        #pragma unroll
        for (int off = 32; off > 0; off >>= 1) s += __shfl_down(s, off);
        if (lane == 0) {
            float v = s + conv_b[0];
            v = (v >= 0.f) ? v : 0.01f * v;        // leaky_relu
            exp_scores[wid] = expf(v);             // scores ~N(0,1): safe
        }
    }

    // --- f32 -> f16 convert (grid-stride float4, coalesced) ---
    const float4* src4 = (const float4*)inlayer;
    uint2* dst2 = (uint2*)hinl;
    for (int i = gtid; i < N_NODES * D / 4; i += NCH * K1T) {
        float4 f = src4[i];
        __half2 h0 = __floats2half2_rn(f.x, f.y);
        __half2 h1 = __floats2half2_rn(f.z, f.w);
        uint2 o; o.x = *(unsigned*)&h0; o.y = *(unsigned*)&h1;
        dst2[i] = o;
    }

    // --- partition this block's 2048-edge chunk ---
    for (int i = t; i < NBIN; i += K1T) lcnt[i] = 0;
    __syncthreads();

    int base = blockIdx.x * CH;
    int n = NNZ - base; if (n > CH) n = CH;      // tail chunk = 1280 (mult of 4)
    int base4 = blockIdx.x * (CH / 4);

    int       ebin[K1E];
    unsigned  erank[K1E];
    unsigned long long epack[K1E];
    bool has = (4 * t < n);
    int4 rr, cc, qq;
    if (has) {
        rr = ((const int4*)rows)[base4 + t];
        cc = ((const int4*)cols)[base4 + t];
        qq = ((const int4*)rel)[base4 + t];
    }
    #pragma unroll
    for (int k = 0; k < K1E; ++k) {
        if (has) {
            int r = (k == 0) ? rr.x : (k == 1) ? rr.y : (k == 2) ? rr.z : rr.w;
            int c = (k == 0) ? cc.x : (k == 1) ? cc.y : (k == 2) ? cc.z : cc.w;
            int q = (k == 0) ? qq.x : (k == 1) ? qq.y : (k == 2) ? qq.z : qq.w;
            int b = r >> 7;
            epack[k] = (unsigned long long)(unsigned)c
                     | ((unsigned long long)(unsigned)q << 16)
                     | ((unsigned long long)(unsigned)(r & 127) << 26);
            ebin[k] = b;
            erank[k] = atomicAdd(&lcnt[b], 1u);
        } else ebin[k] = -1;
    }
    __syncthreads();

    // exclusive scan of NBIN=391 counts across 8 waves
    unsigned cb = (t < NBIN) ? lcnt[t] : 0u;
    unsigned v = cb;
    #pragma unroll
    for (int off = 1; off < 64; off <<= 1) {
        unsigned y = __shfl_up(v, off);
        if (lane >= off) v += y;
    }
    if (lane == 63) wsum[w] = v;
    __syncthreads();
    if (t == 0) {
        unsigned acc = 0;
        #pragma unroll
        for (int k = 0; k < 8; ++k) { unsigned tmp = wsum[k]; wsum[k] = acc; acc += tmp; }
    }
    __syncthreads();
    if (t < NBIN) {
        lstart[t] = wsum[w] + (v - cb);
        lgb[t] = atomicAdd(&bincur[t * 16], cb);   // padded cursors: 1/line
    }
    __syncthreads();

    // LDS scatter into bin-sorted order
    #pragma unroll
    for (int k = 0; k < K1E; ++k) {
        if (ebin[k] >= 0) {
            unsigned p = lstart[ebin[k]] + erank[k];
            sbuf[p] = epack[k];
            sbin[p] = (unsigned short)ebin[k];
        }
    }
    __syncthreads();

    // coalesced run writes: consecutive sorted slots -> consecutive global addrs
    #pragma unroll
    for (int k = 0; k < K1E; ++k) {
        int j = k * K1T + t;
        if (j < n) {
            int b = sbin[j];
            unsigned slot = lgb[b] + (unsigned)j - lstart[b];
            if (slot < CAP)
                binbuf[(unsigned long long)b * CAP + slot] = sbuf[j];
        }
    }
}

// ===== K2: per-bin place — single-pass reg staging; writes starts + 4B packs =====
__global__ void __launch_bounds__(PBT)
place_kernel(const unsigned* __restrict__ bincur,
             const unsigned long long* __restrict__ binbuf,
             const float* __restrict__ exp_scores,
             unsigned* __restrict__ starts, unsigned* __restrict__ bpack,
             float* __restrict__ denom) {
    __shared__ unsigned cnt[RB], cur[RB], ex[RB];
    __shared__ unsigned wsum[8];
    __shared__ float    rpart[8];
    __shared__ unsigned sh_binbase;
    int t = threadIdx.x, lane = t & 63, w = t >> 6;
    int b = blockIdx.x;
    int rlo = b * RB;
    unsigned nb = bincur[b * 16]; if (nb > CAP) nb = CAP;
    const unsigned long long* bb = binbuf + (unsigned long long)b * CAP;

    if (t < RB) { cnt[t] = 0; cur[t] = 0; }
    __syncthreads();

    // stage edges in registers (static indexing) + LDS histogram
    unsigned long long epk[PE];
    #pragma unroll
    for (int k = 0; k < PE; ++k) {
        int e = t + k * PBT;
        if (e < (int)nb) {
            unsigned long long pk = bb[e];
            epk[k] = pk;
            atomicAdd(&cnt[(pk >> 26) & 127ULL], 1u);
        }
    }

    // bin base = sum of earlier bins' counts (512-thread reduce)
    unsigned bv = (t < b) ? min(bincur[t * 16], (unsigned)CAP) : 0u;
    #pragma unroll
    for (int off = 32; off > 0; off >>= 1) bv += __shfl_down(bv, off);
    if (lane == 0) wsum[w] = bv;
    __syncthreads();
    if (t == 0) {
        unsigned s = 0;
        #pragma unroll
        for (int k = 0; k < 8; ++k) s += wsum[k];
        sh_binbase = s;
    }
    __syncthreads();

    // exclusive scan of RB=128 row counts
    unsigned c0 = (t < RB) ? cnt[t] : 0u;
    unsigned v = c0;
    #pragma unroll
    for (int off = 1; off < 64; off <<= 1) {
        unsigned y = __shfl_up(v, off);
        if (lane >= off) v += y;
    }
    if (lane == 63) wsum[w] = v;
    __syncthreads();
    if (t == 0) {
        unsigned acc = 0;
        #pragma unroll
        for (int k = 0; k < 8; ++k) { unsigned tmp = wsum[k]; wsum[k] = acc; acc += tmp; }
    }
    __syncthreads();
    unsigned gex = sh_binbase + wsum[w] + (v - c0);
    if (t < RB) ex[t] = gex;
    if (t <= RB && rlo + t <= N_NODES)
        starts[rlo + t] = gex;   // t==RB writes next bin's base (idempotent overlap)
    __syncthreads();

    // place edges from registers: LDS cursors; 4B writes in L2-hot window
    float dsum = 0.f;
    #pragma unroll
    for (int k = 0; k < PE; ++k) {
        int e = t + k * PBT;
        if (e < (int)nb) {
            unsigned long long pk = epk[k];
            int r = (int)((pk >> 26) & 127ULL);
            unsigned lp = (unsigned)(pk & 0x3FFFFFFULL);   // col | rel<<16
            unsigned rank = atomicAdd(&cur[r], 1u);
            bpack[ex[r] + rank] = lp;
            dsum += exp_scores[lp >> 16];
        }
    }
    #pragma unroll
    for (int off = 32; off > 0; off >>= 1) dsum += __shfl_down(dsum, off);
    if (lane == 0) rpart[w] = dsum;
    __syncthreads();
    if (t == 0) {
        float s = 0.f;
        #pragma unroll
        for (int k = 0; k < 8; ++k) s += rpart[k];
        atomicAdd(denom, s);
    }
}

// ===== K3: gather — fp16 rows, 16 lanes/row, 4 rows per load; /denom epilogue =====
__global__ void gather_kernel(const unsigned* __restrict__ starts,
                              const unsigned* __restrict__ bpack,
                              const float* __restrict__ exp_scores,
                              const __half2* __restrict__ hinl,
                              const float* __restrict__ denom,
                              float* __restrict__ out) {
    int node = blockIdx.x * (blockDim.x >> 6) + (threadIdx.x >> 6);
    int lane = threadIdx.x & 63;
    if (node >= N_NODES) return;
    int s = (int)starts[node];
    int e = (int)starts[node + 1];
    int quad = lane >> 4;                  // which of 4 rows per load
    int l16  = lane & 15;                  // 8-dim group within row
    float a0=0.f,a1=0.f,a2=0.f,a3=0.f,a4=0.f,a5=0.f,a6=0.f,a7=0.f;
    for (int base = s; base < e; base += 64) {
        int rem = e - base; if (rem > 64) rem = 64;
        int px = 0, py = 0;
        if (lane < rem) {
            unsigned pk = bpack[base + lane];          // coalesced 256B / 64 edges
            px = (int)(pk & 0xFFFFu);
            py = __float_as_int(exp_scores[pk >> 16]); // 4KB table: L1-resident
        }
        for (int j = 0; j < rem; j += 16) {
            #pragma unroll
            for (int k = 0; k < 16; k += 4) {
                if (j + k < rem) {         // wave-uniform guard
                    int idx = j + k + quad;
                    int   c = __shfl(px, idx);           // 0 beyond rem -> w=0
                    float wv = __int_as_float(__shfl(py, idx));
                    const __half2* hp = hinl + (long)c * (D / 2) + l16 * 4;
                    uint4 hv = *(const uint4*)hp;        // 8 halves (16B)
                    float2 f0 = __half22float2(*(const __half2*)&hv.x);
                    float2 f1 = __half22float2(*(const __half2*)&hv.y);
                    float2 f2 = __half22float2(*(const __half2*)&hv.z);
                    float2 f3 = __half22float2(*(const __half2*)&hv.w);
                    a0 += wv * f0.x; a1 += wv * f0.y;
                    a2 += wv * f1.x; a3 += wv * f1.y;
                    a4 += wv * f2.x; a5 += wv * f2.y;
                    a6 += wv * f3.x; a7 += wv * f3.y;
                }
            }
        }
    }
    #define COMB(x) x += __shfl(x, lane ^ 16); x += __shfl(x, lane ^ 32);
    COMB(a0) COMB(a1) COMB(a2) COMB(a3) COMB(a4) COMB(a5) COMB(a6) COMB(a7)
    #undef COMB
    if (lane < 32) {                       // 32 lanes cover the 512B row store
        float inv = 1.0f / *denom;         // normalization deferred to epilogue
        float4 v;
        int hi = (lane >> 4) & 1;
        if (hi) { v.x = a4*inv; v.y = a5*inv; v.z = a6*inv; v.w = a7*inv; }
        else    { v.x = a0*inv; v.y = a1*inv; v.z = a2*inv; v.w = a3*inv; }
        *(float4*)(out + (long)node * D + l16 * 8 + hi * 4) = v;
    }
}

extern "C" void kernel_launch(void* const* d_in, const int* in_sizes, int n_in,
                              void* d_out, int out_size, void* d_ws, size_t ws_size,
                              hipStream_t stream) {
    const float* inlayer  = (const float*)d_in[0];
    const float* dual     = (const float*)d_in[1];
    const float* conv_w   = (const float*)d_in[2];
    const float* conv_b   = (const float*)d_in[3];
    const int*   edge_idx = (const int*)d_in[4];   // [2, NNZ]: rows then cols
    const int*   edge_rel = (const int*)d_in[5];
    float* out = (float*)d_out;
    const int* rows = edge_idx;
    const int* cols = edge_idx + NNZ;

    // workspace layout (16B aligned) — total ~24.3 MB
    char* ws = (char*)d_ws;
    float*              exp_scores = (float*)             (ws);                 // 4 KB
    float*              denom      = (float*)             (ws + 4096);          // 4 B
    unsigned*           bincur     = (unsigned*)          (ws + 8192);          // 391*16 u32 (line-padded)
    unsigned*           starts     = (unsigned*)          (ws + 36864);         // 50001 u32
    unsigned long long* binbuf     = (unsigned long long*)(ws + 245760);        // 391*2560*8 = 8.0 MB
    unsigned*           bpack      = (unsigned*)          (ws + 245760 + 8007680);            // 3.2 MB
    __half2*            hinl       = (__half2*)           (ws + 245760 + 8007680 + 3200000);  // 12.8 MB

    // zero denom + bincur in one ~29 KB fill
    hipMemsetAsync(ws + 4096, 0, 4096 + NBIN * 64, stream);

    k1_kernel<<<NCH, K1T, 0, stream>>>(rows, cols, edge_rel, dual, conv_w, conv_b,
                                       inlayer, exp_scores, bincur, binbuf, hinl);
    place_kernel<<<NBIN, PBT, 0, stream>>>(bincur, binbuf, exp_scores,
                                           starts, bpack, denom);
    int grid = (N_NODES + 3) / 4;   // 4 waves/block, one node per wave
    gather_kernel<<<grid, 256, 0, stream>>>(starts, bpack, exp_scores,
                                            hinl, denom, out);
}